// Round 7
// baseline (198.195 us; speedup 1.0000x reference)
//
#include <hip/hip_runtime.h>

// MRConv: B=4, C=192, N=10000, K=16, OUT=384
// out[b,o,n] = relu( sum_ch W[o,ch]*feat[b,ch,n] + bias[o] )
// feat[b,2c,n] = x[b,c,n]; feat[b,2c+1,n] = max_k( x[b,c,e0[b,n,k]] - x[b,c,e1[b,n,k]] )
//
// v7: wave-per-node gather with SCALAR addressing. v2/v4/v6 showed occupancy
// is not the lever (best kernel had lowest Occ); the gather was serialized by
// shfl->vaddr->load chains (~50 cyc/load). Now one wave owns one node: the
// 16+16 neighbor indices are wave-uniform -> readfirstlane'd pointer ->
// s_load index lists; row loads are global_load_dwordx2 with SGPR base +
// constant lane voffset (lane le<48 owns channels 4le..4le+3). All loads of
// an 8-k batch are independent -> ~6KB in flight/wave, no shfl, SALU addr.
// LDS write: one ds_write_b128 per lane per node (lane le = feat granule le),
// swizzle slot(n,le) = n*48 + (le+3n)%48 unchanged. GEMM = v2's proven
// 4-wave 6x4 16x16x32 structure, TILE=64.

#define NB   4
#define NC   192
#define NN   10000
#define NK   16
#define NOUT 384
#define K2C  384            // 2*C

typedef short bf16x8 __attribute__((ext_vector_type(8)));  // 8 bf16 = 4 VGPRs
typedef float f32x4  __attribute__((ext_vector_type(4)));

__device__ inline unsigned short f2bf(float f) {
    unsigned int u = __builtin_bit_cast(unsigned int, f);
    u += ((u >> 16) & 1u) + 0x7FFFu;
    return (unsigned short)(u >> 16);
}
__device__ inline float bflo(unsigned int u) {           // low bf16 of dword -> f32
    return __builtin_bit_cast(float, u << 16);
}
__device__ inline float bfhi(unsigned int u) {           // high bf16 of dword -> f32
    return __builtin_bit_cast(float, u & 0xFFFF0000u);
}
// force a pointer into SGPRs (wave-uniform by construction)
__device__ inline unsigned long long uq(unsigned long long a) {
    unsigned int lo = __builtin_amdgcn_readfirstlane((unsigned int)a);
    unsigned int hi = __builtin_amdgcn_readfirstlane((unsigned int)(a >> 32));
    return ((unsigned long long)hi << 32) | lo;
}

// ---------------- K1: prep = transpose x -> xT bf16  +  W f32 -> bf16 ----------------
__global__ __launch_bounds__(256) void k_prep(const float* __restrict__ x,
                                              unsigned short* __restrict__ xT,
                                              const float* __restrict__ w,
                                              unsigned short* __restrict__ wbf) {
    __shared__ unsigned short tile[NC * 65];   // 192 x 64 (+1 pad)
    int bid = blockIdx.x;
    if (bid >= 628) {                          // ---- wconv part ----
        int i = (bid - 628) * 256 + threadIdx.x;       // [0, 36864)
        float4 v = ((const float4*)w)[i];
        uint2 o;
        o.x = (unsigned int)f2bf(v.x) | ((unsigned int)f2bf(v.y) << 16);
        o.y = (unsigned int)f2bf(v.z) | ((unsigned int)f2bf(v.w) << 16);
        ((uint2*)wbf)[i] = o;
        return;
    }
    int b  = bid & 3;
    int nb = (bid >> 2) * 64;
    int t  = threadIdx.x;
    const float* xb = x + (size_t)b * NC * NN;
    for (int i = 0; i < 48; ++i) {             // 192*64/256 = 48
        int idx = i * 256 + t;
        int c  = idx >> 6;
        int nl = idx & 63;
        int n  = nb + nl;
        float v = (n < NN) ? xb[(size_t)c * NN + n] : 0.f;   // coalesced along n
        tile[c * 65 + nl] = f2bf(v);
    }
    __syncthreads();
    unsigned short* xTb = xT + (size_t)b * NN * NC;
    for (int i = 0; i < 48; ++i) {
        int idx = i * 256 + t;
        int nl  = idx / NC;
        int c   = idx - nl * NC;
        int n   = nb + nl;
        if (n < NN) xTb[(size_t)n * NC + c] = tile[c * 65 + nl];  // coalesced along c
    }
}

// ---------------- K2: fused gather + max-relative + GEMM (256 threads) ----------------
__global__ __launch_bounds__(256, 2) void k_fused(const unsigned short* __restrict__ xT,
                                                  const int* __restrict__ eidx,
                                                  const unsigned short* __restrict__ wbf,
                                                  const float* __restrict__ bias,
                                                  float* __restrict__ out) {
    __shared__ unsigned short lds[64 * 48 * 8];   // 3072 granules of 16B = 48 KB
    int bid  = blockIdx.x;
    int b    = bid & 3;                           // XCD-pins xT[b] to 2 XCDs' L2
    int nt   = bid >> 2;                          // 0..156
    int tid  = threadIdx.x;
    int wv   = tid >> 6;                          // wave id 0..3
    int lane = tid & 63;
    int r    = lane & 15;
    int q    = lane >> 4;
    int le   = (lane < 48) ? lane : (lane - 48);  // load slot: channels 4le..4le+3

    // ---- phase 1: gather + max-relative into LDS (wave-per-node) ----
    const uint2* xr2 = (const uint2*)(xT + (size_t)b * NN * NC);   // 48 uint2 per row
    const int* ep0 = eidx + (size_t)b * NN * NK;                          // e0 -> x_j
    const int* ep1 = eidx + (size_t)NB * NN * NK + (size_t)b * NN * NK;   // e1 -> x_i
    int gnb = nt * 64 + wv * 16;                  // this wave's node base

    for (int it = 0; it < 16; ++it) {
        int n = gnb + it;
        if (n >= NN) break;                       // wave-uniform
        // wave-uniform index lists -> SGPR pointer -> scalar loads
        const int*  pj = (const int*) uq((unsigned long long)(ep0 + (size_t)n * NK));
        const int*  pi = (const int*) uq((unsigned long long)(ep1 + (size_t)n * NK));
        const uint2* rc = (const uint2*)uq((unsigned long long)(xr2 + (size_t)n * 48));
        uint2 cv = rc[le];                        // center row, channels 4le..4le+3
        float m0 = -INFINITY, m1 = -INFINITY, m2 = -INFINITY, m3 = -INFINITY;
#pragma unroll
        for (int h = 0; h < 2; ++h) {
            int js[8], is_[8];
#pragma unroll
            for (int k = 0; k < 8; ++k) {         // scalar index fetch (s_load)
                js[k]  = pj[h * 8 + k];
                is_[k] = pi[h * 8 + k];
            }
            uint2 jv[8], iv[8];
#pragma unroll
            for (int k = 0; k < 8; ++k) {         // 16 independent saddr loads
                jv[k] = xr2[(size_t)js[k]  * 48 + le];
                iv[k] = xr2[(size_t)is_[k] * 48 + le];
            }
#pragma unroll
            for (int k = 0; k < 8; ++k) {
                m0 = fmaxf(m0, bflo(jv[k].x) - bflo(iv[k].x));
                m1 = fmaxf(m1, bfhi(jv[k].x) - bfhi(iv[k].x));
                m2 = fmaxf(m2, bflo(jv[k].y) - bflo(iv[k].y));
                m3 = fmaxf(m3, bfhi(jv[k].y) - bfhi(iv[k].y));
            }
        }
        if (lane < 48) {
            // lane le owns feat granule le of row nl: [x|m] pairs for ch 4le..4le+3
            unsigned int d0 = (cv.x & 0xFFFFu) | ((unsigned int)f2bf(m0) << 16);
            unsigned int d1 = (cv.x >> 16)     | ((unsigned int)f2bf(m1) << 16);
            unsigned int d2 = (cv.y & 0xFFFFu) | ((unsigned int)f2bf(m2) << 16);
            unsigned int d3 = (cv.y >> 16)     | ((unsigned int)f2bf(m3) << 16);
            unsigned int nw = (unsigned int)(wv * 16 + it);
            unsigned int s  = nw * 48u + ((unsigned int)le + 3u * nw) % 48u;
            uint4 o; o.x = d0; o.y = d1; o.z = d2; o.w = d3;
            ((uint4*)lds)[s] = o;
        }
    }

    __syncthreads();

    // ---- phase 2: GEMM, 4 waves x (96 out x 64 n) = 6x4 frags of 16x16x32 ----
    const unsigned short* aptr = wbf + (size_t)(wv * 96 + r) * K2C + q * 8;

    unsigned int nbase[4], u0[4];
#pragma unroll
    for (int ni = 0; ni < 4; ++ni) {
        unsigned int n = ni * 16 + r;
        nbase[ni] = n * 48u;
        u0[ni] = ((unsigned int)q + 3u * n) % 48u;
    }

    f32x4 acc[6][4];
#pragma unroll
    for (int mi = 0; mi < 6; ++mi)
#pragma unroll
        for (int ni = 0; ni < 4; ++ni)
            acc[mi][ni] = (f32x4){0.f, 0.f, 0.f, 0.f};

#pragma unroll 2
    for (int t = 0; t < 12; ++t) {
        bf16x8 a[6], bb[4];
#pragma unroll
        for (int mi = 0; mi < 6; ++mi)
            a[mi] = *(const bf16x8*)(aptr + (size_t)mi * 16 * K2C + t * 32);
#pragma unroll
        for (int ni = 0; ni < 4; ++ni) {
            unsigned int u = u0[ni] + 4u * t;
            if (u >= 48u) u -= 48u;
            bb[ni] = *(const bf16x8*)(lds + (size_t)(nbase[ni] + u) * 8);
        }
#pragma unroll
        for (int mi = 0; mi < 6; ++mi)
#pragma unroll
            for (int ni = 0; ni < 4; ++ni)
                acc[mi][ni] = __builtin_amdgcn_mfma_f32_16x16x32_bf16(a[mi], bb[ni], acc[mi][ni], 0, 0, 0);
    }

    float* ob = out + (size_t)b * NOUT * NN;
#pragma unroll
    for (int mi = 0; mi < 6; ++mi) {
        int obase = wv * 96 + mi * 16 + q * 4;
#pragma unroll
        for (int ni = 0; ni < 4; ++ni) {
            int n = nt * 64 + ni * 16 + r;
            if (n < NN) {
#pragma unroll
                for (int rr = 0; rr < 4; ++rr) {
                    int o = obase + rr;
                    float val = acc[mi][ni][rr] + bias[o];
                    ob[(size_t)o * NN + n] = fmaxf(val, 0.f);
                }
            }
        }
    }
}

extern "C" void kernel_launch(void* const* d_in, const int* in_sizes, int n_in,
                              void* d_out, int out_size, void* d_ws, size_t ws_size,
                              hipStream_t stream) {
    const float* x    = (const float*)d_in[0];   // [4,192,10000,1]
    const int*   eidx = (const int*)d_in[1];     // [2,4,10000,16]
    const float* w    = (const float*)d_in[2];   // [384,384]
    const float* bias = (const float*)d_in[3];   // [384]
    float* out = (float*)d_out;                  // [4,384,10000,1,1]

    // workspace: xT [4][10000][192] bf16 (15.36 MB) | wbf [384][384] bf16 (0.29 MB)
    unsigned short* xT  = (unsigned short*)d_ws;
    unsigned short* wbf = xT + (size_t)NB * NN * NC;

    hipLaunchKernelGGL(k_prep,  dim3(628 + 144), dim3(256), 0, stream, x, xT, w, wbf);
    hipLaunchKernelGGL(k_fused, dim3(4 * 157),   dim3(256), 0, stream, xT, eidx, wbf, bias, out);
}

// Round 8
// 195.468 us; speedup vs baseline: 1.0139x; 1.0139x over previous
//
#include <hip/hip_runtime.h>

// MRConv: B=4, C=192, N=10000, K=16, OUT=384
// out[b,o,n] = relu( sum_ch W[o,ch]*feat[b,ch,n] + bias[o] )
// feat[b,2c,n] = x[b,c,n]; feat[b,2c+1,n] = max_k( x[b,c,e0[b,n,k]] - x[b,c,e1[b,n,k]] )
//
// v8: wave-per-node gather, VECTOR index fetch + readlane broadcast.
// v7's scalar s_load index path serialized every node iteration on a
// scalar-cache miss (~500cyc, lgkm drain). Now: indices hoisted via one
// coalesced vector load per node (lane k = e0[n,k], lane 16+k = e1[n,k]),
// broadcast with __builtin_amdgcn_readlane (VALU, no memory) -> row loads
// are global_load_dwordx2 with uniform base + lane*8, 33 independent per
// node, issued in two 16-deep batches (~12KB in flight/wave). Lanes 48-63
// exec-masked (no v7 duplicate traffic). it-loop fully unrolled so vv[it]
// is statically indexed (no scratch). GEMM = v2's proven 4-wave 6x4
// 16x16x32 structure, TILE=64, swizzled LDS (slot = n*48 + (g+3n)%48).

#define NB   4
#define NC   192
#define NN   10000
#define NK   16
#define NOUT 384
#define K2C  384            // 2*C

typedef short bf16x8 __attribute__((ext_vector_type(8)));  // 8 bf16 = 4 VGPRs
typedef float f32x4  __attribute__((ext_vector_type(4)));

__device__ inline unsigned short f2bf(float f) {
    unsigned int u = __builtin_bit_cast(unsigned int, f);
    u += ((u >> 16) & 1u) + 0x7FFFu;
    return (unsigned short)(u >> 16);
}
__device__ inline float bflo(unsigned int u) {           // low bf16 of dword -> f32
    return __builtin_bit_cast(float, u << 16);
}
__device__ inline float bfhi(unsigned int u) {           // high bf16 of dword -> f32
    return __builtin_bit_cast(float, u & 0xFFFF0000u);
}

// ---------------- K1: prep = transpose x -> xT bf16  +  W f32 -> bf16 ----------------
__global__ __launch_bounds__(256) void k_prep(const float* __restrict__ x,
                                              unsigned short* __restrict__ xT,
                                              const float* __restrict__ w,
                                              unsigned short* __restrict__ wbf) {
    __shared__ unsigned short tile[NC * 65];   // 192 x 64 (+1 pad)
    int bid = blockIdx.x;
    if (bid >= 628) {                          // ---- wconv part ----
        int i = (bid - 628) * 256 + threadIdx.x;       // [0, 36864)
        float4 v = ((const float4*)w)[i];
        uint2 o;
        o.x = (unsigned int)f2bf(v.x) | ((unsigned int)f2bf(v.y) << 16);
        o.y = (unsigned int)f2bf(v.z) | ((unsigned int)f2bf(v.w) << 16);
        ((uint2*)wbf)[i] = o;
        return;
    }
    int b  = bid & 3;
    int nb = (bid >> 2) * 64;
    int t  = threadIdx.x;
    const float* xb = x + (size_t)b * NC * NN;
    for (int i = 0; i < 48; ++i) {             // 192*64/256 = 48
        int idx = i * 256 + t;
        int c  = idx >> 6;
        int nl = idx & 63;
        int n  = nb + nl;
        float v = (n < NN) ? xb[(size_t)c * NN + n] : 0.f;   // coalesced along n
        tile[c * 65 + nl] = f2bf(v);
    }
    __syncthreads();
    unsigned short* xTb = xT + (size_t)b * NN * NC;
    for (int i = 0; i < 48; ++i) {
        int idx = i * 256 + t;
        int nl  = idx / NC;
        int c   = idx - nl * NC;
        int n   = nb + nl;
        if (n < NN) xTb[(size_t)n * NC + c] = tile[c * 65 + nl];  // coalesced along c
    }
}

// ---------------- K2: fused gather + max-relative + GEMM (256 threads) ----------------
__global__ __launch_bounds__(256, 2) void k_fused(const unsigned short* __restrict__ xT,
                                                  const int* __restrict__ eidx,
                                                  const unsigned short* __restrict__ wbf,
                                                  const float* __restrict__ bias,
                                                  float* __restrict__ out) {
    __shared__ unsigned short lds[64 * 48 * 8];   // 3072 granules of 16B = 48 KB
    int bid  = blockIdx.x;
    int b    = bid & 3;                           // XCD-pins xT[b] to 2 XCDs' L2
    int nt   = bid >> 2;                          // 0..156
    int tid  = threadIdx.x;
    int wv   = tid >> 6;                          // wave id 0..3
    int lane = tid & 63;
    int r    = lane & 15;
    int q    = lane >> 4;

    // ---- phase 1: gather + max-relative into LDS (wave-per-node) ----
    const uint2* xr2 = (const uint2*)(xT + (size_t)b * NN * NC);   // 48 uint2 per row
    const int* ep0 = eidx + (size_t)b * NN * NK;                          // e0 -> x_j
    const int* ep1 = eidx + (size_t)NB * NN * NK + (size_t)b * NN * NK;   // e1 -> x_i
    int gnb = nt * 64 + wv * 16;                  // this wave's node base

    // hoisted index vectors: vv[it] lane k (k<16) = e0[n,k]; lane 16+k = e1[n,k]
    const int* epsel = (lane & 16) ? ep1 : ep0;
    int kslot = lane & 15;
    int vv[16];
#pragma unroll
    for (int it = 0; it < 16; ++it) {
        int n = gnb + it;
        vv[it] = (lane < 32 && n < NN) ? epsel[(size_t)n * NK + kslot] : 0;
    }

#pragma unroll
    for (int it = 0; it < 16; ++it) {
        int n = gnb + it;
        if (n < NN) {                             // wave-uniform guard
            int nl = wv * 16 + it;
            if (lane < 48) {
                uint2 cv = xr2[(size_t)n * 48 + lane];  // center row, ch 4l..4l+3
                uint2 ja[8], ia[8], jb[8], ib[8];
#pragma unroll
                for (int k = 0; k < 8; ++k) {     // batch A: k=0..7, 16 indep loads
                    int j = __builtin_amdgcn_readlane(vv[it], k);
                    int i = __builtin_amdgcn_readlane(vv[it], 16 + k);
                    ja[k] = xr2[(size_t)j * 48 + lane];
                    ia[k] = xr2[(size_t)i * 48 + lane];
                }
#pragma unroll
                for (int k = 0; k < 8; ++k) {     // batch B: k=8..15
                    int j = __builtin_amdgcn_readlane(vv[it], 8 + k);
                    int i = __builtin_amdgcn_readlane(vv[it], 24 + k);
                    jb[k] = xr2[(size_t)j * 48 + lane];
                    ib[k] = xr2[(size_t)i * 48 + lane];
                }
                float m0 = -INFINITY, m1 = -INFINITY, m2 = -INFINITY, m3 = -INFINITY;
#pragma unroll
                for (int k = 0; k < 8; ++k) {
                    m0 = fmaxf(m0, bflo(ja[k].x) - bflo(ia[k].x));
                    m1 = fmaxf(m1, bfhi(ja[k].x) - bfhi(ia[k].x));
                    m2 = fmaxf(m2, bflo(ja[k].y) - bflo(ia[k].y));
                    m3 = fmaxf(m3, bfhi(ja[k].y) - bfhi(ia[k].y));
                }
#pragma unroll
                for (int k = 0; k < 8; ++k) {
                    m0 = fmaxf(m0, bflo(jb[k].x) - bflo(ib[k].x));
                    m1 = fmaxf(m1, bfhi(jb[k].x) - bfhi(ib[k].x));
                    m2 = fmaxf(m2, bflo(jb[k].y) - bflo(ib[k].y));
                    m3 = fmaxf(m3, bfhi(jb[k].y) - bfhi(ib[k].y));
                }
                // lane owns feat granule `lane` of row nl: (x|m) pairs, ch 4l..4l+3
                unsigned int d0 = (cv.x & 0xFFFFu) | ((unsigned int)f2bf(m0) << 16);
                unsigned int d1 = (cv.x >> 16)     | ((unsigned int)f2bf(m1) << 16);
                unsigned int d2 = (cv.y & 0xFFFFu) | ((unsigned int)f2bf(m2) << 16);
                unsigned int d3 = (cv.y >> 16)     | ((unsigned int)f2bf(m3) << 16);
                unsigned int nw = (unsigned int)nl;
                unsigned int s  = nw * 48u + ((unsigned int)lane + 3u * nw) % 48u;
                uint4 o; o.x = d0; o.y = d1; o.z = d2; o.w = d3;
                ((uint4*)lds)[s] = o;
            }
        }
    }

    __syncthreads();

    // ---- phase 2: GEMM, 4 waves x (96 out x 64 n) = 6x4 frags of 16x16x32 ----
    const unsigned short* aptr = wbf + (size_t)(wv * 96 + r) * K2C + q * 8;

    unsigned int nbase[4], u0[4];
#pragma unroll
    for (int ni = 0; ni < 4; ++ni) {
        unsigned int n = ni * 16 + r;
        nbase[ni] = n * 48u;
        u0[ni] = ((unsigned int)q + 3u * n) % 48u;
    }

    f32x4 acc[6][4];
#pragma unroll
    for (int mi = 0; mi < 6; ++mi)
#pragma unroll
        for (int ni = 0; ni < 4; ++ni)
            acc[mi][ni] = (f32x4){0.f, 0.f, 0.f, 0.f};

#pragma unroll 2
    for (int t = 0; t < 12; ++t) {
        bf16x8 a[6], bb[4];
#pragma unroll
        for (int mi = 0; mi < 6; ++mi)
            a[mi] = *(const bf16x8*)(aptr + (size_t)mi * 16 * K2C + t * 32);
#pragma unroll
        for (int ni = 0; ni < 4; ++ni) {
            unsigned int u = u0[ni] + 4u * t;
            if (u >= 48u) u -= 48u;
            bb[ni] = *(const bf16x8*)(lds + (size_t)(nbase[ni] + u) * 8);
        }
#pragma unroll
        for (int mi = 0; mi < 6; ++mi)
#pragma unroll
            for (int ni = 0; ni < 4; ++ni)
                acc[mi][ni] = __builtin_amdgcn_mfma_f32_16x16x32_bf16(a[mi], bb[ni], acc[mi][ni], 0, 0, 0);
    }

    float* ob = out + (size_t)b * NOUT * NN;
#pragma unroll
    for (int mi = 0; mi < 6; ++mi) {
        int obase = wv * 96 + mi * 16 + q * 4;
#pragma unroll
        for (int ni = 0; ni < 4; ++ni) {
            int n = nt * 64 + ni * 16 + r;
            if (n < NN) {
#pragma unroll
                for (int rr = 0; rr < 4; ++rr) {
                    int o = obase + rr;
                    float val = acc[mi][ni][rr] + bias[o];
                    ob[(size_t)o * NN + n] = fmaxf(val, 0.f);
                }
            }
        }
    }
}

extern "C" void kernel_launch(void* const* d_in, const int* in_sizes, int n_in,
                              void* d_out, int out_size, void* d_ws, size_t ws_size,
                              hipStream_t stream) {
    const float* x    = (const float*)d_in[0];   // [4,192,10000,1]
    const int*   eidx = (const int*)d_in[1];     // [2,4,10000,16]
    const float* w    = (const float*)d_in[2];   // [384,384]
    const float* bias = (const float*)d_in[3];   // [384]
    float* out = (float*)d_out;                  // [4,384,10000,1,1]

    // workspace: xT [4][10000][192] bf16 (15.36 MB) | wbf [384][384] bf16 (0.29 MB)
    unsigned short* xT  = (unsigned short*)d_ws;
    unsigned short* wbf = xT + (size_t)NB * NN * NC;

    hipLaunchKernelGGL(k_prep,  dim3(628 + 144), dim3(256), 0, stream, x, xT, w, wbf);
    hipLaunchKernelGGL(k_fused, dim3(4 * 157),   dim3(256), 0, stream, xT, eidx, wbf, bias, out);
}

// Round 9
// 166.982 us; speedup vs baseline: 1.1869x; 1.1706x over previous
//
#include <hip/hip_runtime.h>

// MRConv: B=4, C=192, N=10000, K=16, OUT=384
// out[b,o,n] = relu( sum_ch W[o,ch]*feat[b,ch,n] + bias[o] )
// feat[b,2c,n] = x[b,c,n]; feat[b,2c+1,n] = max_k( x[b,c,e0[b,n,k]] - x[b,c,e1[b,n,k]] )
//
// v9: v2 (the 61us anchor; half-wave-per-node gather, trickle access = no L2
// thrash) with 4 surgical gather fixes:
//  1. packed (i<<16)|j index hoist -> ONE shfl per k (was 2 bpermutes)
//  2. k-loop unroll 8 (48 loads in flight per half-wave, was 24)
//  3. it-loop unroll 2 (break->guard): next node's loads issue under previous
//     node's fmax tail -> kills the per-node pipeline bubble
//  4. __umul24 row addressing (indices < 2^24)
// GEMM phase, LDS swizzle, launch config byte-identical to v2.

#define NB   4
#define NC   192
#define NN   10000
#define NK   16
#define NOUT 384
#define K2C  384            // 2*C

typedef short bf16x8 __attribute__((ext_vector_type(8)));  // 8 bf16 = 4 VGPRs
typedef float f32x4  __attribute__((ext_vector_type(4)));

__device__ inline unsigned short f2bf(float f) {
    unsigned int u = __builtin_bit_cast(unsigned int, f);
    u += ((u >> 16) & 1u) + 0x7FFFu;
    return (unsigned short)(u >> 16);
}
__device__ inline float bflo(unsigned int u) {           // low bf16 of dword -> f32
    return __builtin_bit_cast(float, u << 16);
}
__device__ inline float bfhi(unsigned int u) {           // high bf16 of dword -> f32
    return __builtin_bit_cast(float, u & 0xFFFF0000u);
}

// ---------------- K1: prep = transpose x -> xT bf16  +  W f32 -> bf16 ----------------
__global__ __launch_bounds__(256) void k_prep(const float* __restrict__ x,
                                              unsigned short* __restrict__ xT,
                                              const float* __restrict__ w,
                                              unsigned short* __restrict__ wbf) {
    __shared__ unsigned short tile[NC * 65];   // 192 x 64 (+1 pad)
    int bid = blockIdx.x;
    if (bid >= 628) {                          // ---- wconv part ----
        int i = (bid - 628) * 256 + threadIdx.x;       // [0, 36864)
        float4 v = ((const float4*)w)[i];
        uint2 o;
        o.x = (unsigned int)f2bf(v.x) | ((unsigned int)f2bf(v.y) << 16);
        o.y = (unsigned int)f2bf(v.z) | ((unsigned int)f2bf(v.w) << 16);
        ((uint2*)wbf)[i] = o;
        return;
    }
    int b  = bid & 3;
    int nb = (bid >> 2) * 64;
    int t  = threadIdx.x;
    const float* xb = x + (size_t)b * NC * NN;
    for (int i = 0; i < 48; ++i) {             // 192*64/256 = 48
        int idx = i * 256 + t;
        int c  = idx >> 6;
        int nl = idx & 63;
        int n  = nb + nl;
        float v = (n < NN) ? xb[(size_t)c * NN + n] : 0.f;   // coalesced along n
        tile[c * 65 + nl] = f2bf(v);
    }
    __syncthreads();
    unsigned short* xTb = xT + (size_t)b * NN * NC;
    for (int i = 0; i < 48; ++i) {
        int idx = i * 256 + t;
        int nl  = idx / NC;
        int c   = idx - nl * NC;
        int n   = nb + nl;
        if (n < NN) xTb[(size_t)n * NC + c] = tile[c * 65 + nl];  // coalesced along c
    }
}

// ---------------- K2: fused gather + max-relative + GEMM (256 threads) ----------------
// Phase 1 (gather): half-wave (32 lanes) per node, 8 nodes each; dword (2-ch)
// loads; packed (x|m) dwords into swizzled LDS granules slot(n,j)=n*48+(j+3n)%48.
// Phase 2 (GEMM): 4 waves x (96 out x 64 n) = 6x4 frags of 16x16x32 bf16.
__global__ __launch_bounds__(256, 2) void k_fused(const unsigned short* __restrict__ xT,
                                                  const int* __restrict__ eidx,
                                                  const unsigned short* __restrict__ wbf,
                                                  const float* __restrict__ bias,
                                                  float* __restrict__ out) {
    __shared__ unsigned short lds[64 * 48 * 8];   // 3072 granules of 16B = 48 KB
    int bid  = blockIdx.x;
    int b    = bid & 3;                           // XCD-pins xT[b] to 2 XCDs' L2
    int nt   = bid >> 2;                          // 0..156
    int tid  = threadIdx.x;
    int wv   = tid >> 6;                          // wave id 0..3
    int lane = tid & 63;
    int lam  = lane & 31;                         // lane within half-wave
    int hb   = lane & 32;                         // half-wave base for shfl
    int r    = lane & 15;
    int q    = lane >> 4;

    // ---- phase 1: gather + max-relative into LDS ----
    const unsigned int* xr = (const unsigned int*)(xT + (size_t)b * NN * NC); // rows of 96 dwords
    const int* ep0 = eidx + (size_t)b * NN * NK;                          // e0 -> x_j
    const int* ep1 = eidx + (size_t)NB * NN * NK + (size_t)b * NN * NK;   // e1 -> x_i
    int nlb = wv * 16 + (hb ? 8 : 0);             // local node base
    int gnb = nt * 64 + nlb;                      // global node base

    // hoist packed index vectors: lane lam<16 holds (e1[n,lam]<<16)|e0[n,lam]
    unsigned int vp[8];
#pragma unroll
    for (int it = 0; it < 8; ++it) {
        int n = gnb + it;
        unsigned int jj = 0, ii = 0;
        if (lam < 16 && n < NN) {
            jj = (unsigned int)ep0[(size_t)n * NK + lam];
            ii = (unsigned int)ep1[(size_t)n * NK + lam];
        }
        vp[it] = (ii << 16) | jj;
    }

    uint2* l2 = (uint2*)lds;                      // 2 uint2 per granule
#pragma unroll 2
    for (int it = 0; it < 8; ++it) {
        int n = gnb + it;
        if (n < NN) {                             // uniform within half-wave
            int nl = nlb + it;
            unsigned int nrow = (unsigned int)n * 96u;
            unsigned int c0 = xr[nrow + lam], c1 = xr[nrow + 32 + lam], c2 = xr[nrow + 64 + lam];
            float m0l = -INFINITY, m0h = -INFINITY;
            float m1l = -INFINITY, m1h = -INFINITY;
            float m2l = -INFINITY, m2h = -INFINITY;
#pragma unroll 8
            for (int k = 0; k < 16; ++k) {
                unsigned int p = (unsigned int)__shfl((int)vp[it], hb + k, 64);
                unsigned int j = p & 0xFFFFu;
                unsigned int i = p >> 16;
                unsigned int ja = __umul24(j, 96u) + (unsigned int)lam;
                unsigned int ia = __umul24(i, 96u) + (unsigned int)lam;
                unsigned int j0 = xr[ja], j1 = xr[ja + 32], j2 = xr[ja + 64];
                unsigned int i0 = xr[ia], i1 = xr[ia + 32], i2 = xr[ia + 64];
                m0l = fmaxf(m0l, bflo(j0) - bflo(i0));  m0h = fmaxf(m0h, bfhi(j0) - bfhi(i0));
                m1l = fmaxf(m1l, bflo(j1) - bflo(i1));  m1h = fmaxf(m1h, bfhi(j1) - bfhi(i1));
                m2l = fmaxf(m2l, bflo(j2) - bflo(i2));  m2h = fmaxf(m2h, bfhi(j2) - bfhi(i2));
            }
            // feat dwords: lane's c-dword d -> feat channels [4*lane_d, 4*lane_d+4)
            uint2 o0, o1, o2;
            o0.x = (c0 & 0xFFFFu)  | ((unsigned int)f2bf(m0l) << 16);
            o0.y = (c0 >> 16)      | ((unsigned int)f2bf(m0h) << 16);
            o1.x = (c1 & 0xFFFFu)  | ((unsigned int)f2bf(m1l) << 16);
            o1.y = (c1 >> 16)      | ((unsigned int)f2bf(m1h) << 16);
            o2.x = (c2 & 0xFFFFu)  | ((unsigned int)f2bf(m2l) << 16);
            o2.y = (c2 >> 16)      | ((unsigned int)f2bf(m2h) << 16);
            // granule j for o0 = lam>>1; o1 = 16+lam>>1; o2 = 32+lam>>1; half = lam&1
            unsigned int g  = (unsigned int)(lam >> 1);
            unsigned int nw = (unsigned int)nl;
            unsigned int s0 = nw * 48u + (g        + 3u * nw) % 48u;
            unsigned int s1 = nw * 48u + (g + 16u  + 3u * nw) % 48u;
            unsigned int s2 = nw * 48u + (g + 32u  + 3u * nw) % 48u;
            unsigned int half = (unsigned int)(lam & 1);
            l2[2u * s0 + half] = o0;
            l2[2u * s1 + half] = o1;
            l2[2u * s2 + half] = o2;
        }
    }

    __syncthreads();

    // ---- phase 2: GEMM, 4 waves x (96 out x 64 n) = 6x4 frags of 16x16x32 ----
    const unsigned short* aptr = wbf + (size_t)(wv * 96 + r) * K2C + q * 8;

    unsigned int nbase[4], u0[4];
#pragma unroll
    for (int ni = 0; ni < 4; ++ni) {
        unsigned int n = ni * 16 + r;
        nbase[ni] = n * 48u;
        u0[ni] = ((unsigned int)q + 3u * n) % 48u;
    }

    f32x4 acc[6][4];
#pragma unroll
    for (int mi = 0; mi < 6; ++mi)
#pragma unroll
        for (int ni = 0; ni < 4; ++ni)
            acc[mi][ni] = (f32x4){0.f, 0.f, 0.f, 0.f};

#pragma unroll 2
    for (int t = 0; t < 12; ++t) {
        bf16x8 a[6], bb[4];
#pragma unroll
        for (int mi = 0; mi < 6; ++mi)
            a[mi] = *(const bf16x8*)(aptr + (size_t)mi * 16 * K2C + t * 32);
#pragma unroll
        for (int ni = 0; ni < 4; ++ni) {
            unsigned int u = u0[ni] + 4u * t;
            if (u >= 48u) u -= 48u;
            bb[ni] = *(const bf16x8*)(lds + (size_t)(nbase[ni] + u) * 8);
        }
#pragma unroll
        for (int mi = 0; mi < 6; ++mi)
#pragma unroll
            for (int ni = 0; ni < 4; ++ni)
                acc[mi][ni] = __builtin_amdgcn_mfma_f32_16x16x32_bf16(a[mi], bb[ni], acc[mi][ni], 0, 0, 0);
    }

    float* ob = out + (size_t)b * NOUT * NN;
#pragma unroll
    for (int mi = 0; mi < 6; ++mi) {
        int obase = wv * 96 + mi * 16 + q * 4;
#pragma unroll
        for (int ni = 0; ni < 4; ++ni) {
            int n = nt * 64 + ni * 16 + r;
            if (n < NN) {
#pragma unroll
                for (int rr = 0; rr < 4; ++rr) {
                    int o = obase + rr;
                    float val = acc[mi][ni][rr] + bias[o];
                    ob[(size_t)o * NN + n] = fmaxf(val, 0.f);
                }
            }
        }
    }
}

extern "C" void kernel_launch(void* const* d_in, const int* in_sizes, int n_in,
                              void* d_out, int out_size, void* d_ws, size_t ws_size,
                              hipStream_t stream) {
    const float* x    = (const float*)d_in[0];   // [4,192,10000,1]
    const int*   eidx = (const int*)d_in[1];     // [2,4,10000,16]
    const float* w    = (const float*)d_in[2];   // [384,384]
    const float* bias = (const float*)d_in[3];   // [384]
    float* out = (float*)d_out;                  // [4,384,10000,1,1]

    // workspace: xT [4][10000][192] bf16 (15.36 MB) | wbf [384][384] bf16 (0.29 MB)
    unsigned short* xT  = (unsigned short*)d_ws;
    unsigned short* wbf = xT + (size_t)NB * NN * NC;

    hipLaunchKernelGGL(k_prep,  dim3(628 + 144), dim3(256), 0, stream, x, xT, w, wbf);
    hipLaunchKernelGGL(k_fused, dim3(4 * 157),   dim3(256), 0, stream, xT, eidx, wbf, bias, out);
}

// Round 10
// 164.732 us; speedup vs baseline: 1.2031x; 1.0137x over previous
//
#include <hip/hip_runtime.h>

// MRConv: B=4, C=192, N=10000, K=16, OUT=384
// out[b,o,n] = relu( sum_ch W[o,ch]*feat[b,ch,n] + bias[o] )
// feat[b,2c,n] = x[b,c,n]; feat[b,2c+1,n] = max_k( x[b,c,e0[b,n,k]] - x[b,c,e1[b,n,k]] )
//
// v10: v9 + agent-scope (sc0) loads for the random neighbor-row gather.
// Measured 19.4 cyc/VMEM-instr == MSHR model (32 miss-lines/CU, 2 lines/instr,
// ~300cyc L2 latency -> 18.8 cyc/instr). Occupancy/ILP experiments (v3-v8)
// all flat-or-worse -> cap is per-CU L1 miss tracking, not wave concurrency.
// __hip_atomic_load(relaxed, agent) emits global_load_dword sc0: bypasses L1
// (and its MSHR pool), L2 policy unchanged (unlike nt/slc which evict-first
// and would flush xT's L2 residency). Applied ONLY to the 96 random j/i row
// loads per node; center/eidx/W/GEMM keep normal caching.
// Everything else byte-identical to v9.

#define NB   4
#define NC   192
#define NN   10000
#define NK   16
#define NOUT 384
#define K2C  384            // 2*C

typedef short bf16x8 __attribute__((ext_vector_type(8)));  // 8 bf16 = 4 VGPRs
typedef float f32x4  __attribute__((ext_vector_type(4)));

__device__ inline unsigned short f2bf(float f) {
    unsigned int u = __builtin_bit_cast(unsigned int, f);
    u += ((u >> 16) & 1u) + 0x7FFFu;
    return (unsigned short)(u >> 16);
}
__device__ inline float bflo(unsigned int u) {           // low bf16 of dword -> f32
    return __builtin_bit_cast(float, u << 16);
}
__device__ inline float bfhi(unsigned int u) {           // high bf16 of dword -> f32
    return __builtin_bit_cast(float, u & 0xFFFF0000u);
}
// agent-scope load: global_load_dword sc0 -> L1-bypass, L2-normal
__device__ inline unsigned int ld_sc0(const unsigned int* p) {
    return __hip_atomic_load(p, __ATOMIC_RELAXED, __HIP_MEMORY_SCOPE_AGENT);
}

// ---------------- K1: prep = transpose x -> xT bf16  +  W f32 -> bf16 ----------------
__global__ __launch_bounds__(256) void k_prep(const float* __restrict__ x,
                                              unsigned short* __restrict__ xT,
                                              const float* __restrict__ w,
                                              unsigned short* __restrict__ wbf) {
    __shared__ unsigned short tile[NC * 65];   // 192 x 64 (+1 pad)
    int bid = blockIdx.x;
    if (bid >= 628) {                          // ---- wconv part ----
        int i = (bid - 628) * 256 + threadIdx.x;       // [0, 36864)
        float4 v = ((const float4*)w)[i];
        uint2 o;
        o.x = (unsigned int)f2bf(v.x) | ((unsigned int)f2bf(v.y) << 16);
        o.y = (unsigned int)f2bf(v.z) | ((unsigned int)f2bf(v.w) << 16);
        ((uint2*)wbf)[i] = o;
        return;
    }
    int b  = bid & 3;
    int nb = (bid >> 2) * 64;
    int t  = threadIdx.x;
    const float* xb = x + (size_t)b * NC * NN;
    for (int i = 0; i < 48; ++i) {             // 192*64/256 = 48
        int idx = i * 256 + t;
        int c  = idx >> 6;
        int nl = idx & 63;
        int n  = nb + nl;
        float v = (n < NN) ? xb[(size_t)c * NN + n] : 0.f;   // coalesced along n
        tile[c * 65 + nl] = f2bf(v);
    }
    __syncthreads();
    unsigned short* xTb = xT + (size_t)b * NN * NC;
    for (int i = 0; i < 48; ++i) {
        int idx = i * 256 + t;
        int nl  = idx / NC;
        int c   = idx - nl * NC;
        int n   = nb + nl;
        if (n < NN) xTb[(size_t)n * NC + c] = tile[c * 65 + nl];  // coalesced along c
    }
}

// ---------------- K2: fused gather + max-relative + GEMM (256 threads) ----------------
// Phase 1 (gather): half-wave (32 lanes) per node, 8 nodes each; dword (2-ch)
// loads; packed (x|m) dwords into swizzled LDS granules slot(n,j)=n*48+(j+3n)%48.
// Phase 2 (GEMM): 4 waves x (96 out x 64 n) = 6x4 frags of 16x16x32 bf16.
__global__ __launch_bounds__(256, 2) void k_fused(const unsigned short* __restrict__ xT,
                                                  const int* __restrict__ eidx,
                                                  const unsigned short* __restrict__ wbf,
                                                  const float* __restrict__ bias,
                                                  float* __restrict__ out) {
    __shared__ unsigned short lds[64 * 48 * 8];   // 3072 granules of 16B = 48 KB
    int bid  = blockIdx.x;
    int b    = bid & 3;                           // XCD-pins xT[b] to 2 XCDs' L2
    int nt   = bid >> 2;                          // 0..156
    int tid  = threadIdx.x;
    int wv   = tid >> 6;                          // wave id 0..3
    int lane = tid & 63;
    int lam  = lane & 31;                         // lane within half-wave
    int hb   = lane & 32;                         // half-wave base for shfl
    int r    = lane & 15;
    int q    = lane >> 4;

    // ---- phase 1: gather + max-relative into LDS ----
    const unsigned int* xr = (const unsigned int*)(xT + (size_t)b * NN * NC); // rows of 96 dwords
    const int* ep0 = eidx + (size_t)b * NN * NK;                          // e0 -> x_j
    const int* ep1 = eidx + (size_t)NB * NN * NK + (size_t)b * NN * NK;   // e1 -> x_i
    int nlb = wv * 16 + (hb ? 8 : 0);             // local node base
    int gnb = nt * 64 + nlb;                      // global node base

    // hoist packed index vectors: lane lam<16 holds (e1[n,lam]<<16)|e0[n,lam]
    unsigned int vp[8];
#pragma unroll
    for (int it = 0; it < 8; ++it) {
        int n = gnb + it;
        unsigned int jj = 0, ii = 0;
        if (lam < 16 && n < NN) {
            jj = (unsigned int)ep0[(size_t)n * NK + lam];
            ii = (unsigned int)ep1[(size_t)n * NK + lam];
        }
        vp[it] = (ii << 16) | jj;
    }

    uint2* l2 = (uint2*)lds;                      // 2 uint2 per granule
#pragma unroll 2
    for (int it = 0; it < 8; ++it) {
        int n = gnb + it;
        if (n < NN) {                             // uniform within half-wave
            int nl = nlb + it;
            unsigned int nrow = (unsigned int)n * 96u;
            unsigned int c0 = xr[nrow + lam], c1 = xr[nrow + 32 + lam], c2 = xr[nrow + 64 + lam];
            float m0l = -INFINITY, m0h = -INFINITY;
            float m1l = -INFINITY, m1h = -INFINITY;
            float m2l = -INFINITY, m2h = -INFINITY;
#pragma unroll 8
            for (int k = 0; k < 16; ++k) {
                unsigned int p = (unsigned int)__shfl((int)vp[it], hb + k, 64);
                unsigned int j = p & 0xFFFFu;
                unsigned int i = p >> 16;
                unsigned int ja = __umul24(j, 96u) + (unsigned int)lam;
                unsigned int ia = __umul24(i, 96u) + (unsigned int)lam;
                unsigned int j0 = ld_sc0(&xr[ja]);
                unsigned int j1 = ld_sc0(&xr[ja + 32]);
                unsigned int j2 = ld_sc0(&xr[ja + 64]);
                unsigned int i0 = ld_sc0(&xr[ia]);
                unsigned int i1 = ld_sc0(&xr[ia + 32]);
                unsigned int i2 = ld_sc0(&xr[ia + 64]);
                m0l = fmaxf(m0l, bflo(j0) - bflo(i0));  m0h = fmaxf(m0h, bfhi(j0) - bfhi(i0));
                m1l = fmaxf(m1l, bflo(j1) - bflo(i1));  m1h = fmaxf(m1h, bfhi(j1) - bfhi(i1));
                m2l = fmaxf(m2l, bflo(j2) - bflo(i2));  m2h = fmaxf(m2h, bfhi(j2) - bfhi(i2));
            }
            // feat dwords: lane's c-dword d -> feat channels [4*lane_d, 4*lane_d+4)
            uint2 o0, o1, o2;
            o0.x = (c0 & 0xFFFFu)  | ((unsigned int)f2bf(m0l) << 16);
            o0.y = (c0 >> 16)      | ((unsigned int)f2bf(m0h) << 16);
            o1.x = (c1 & 0xFFFFu)  | ((unsigned int)f2bf(m1l) << 16);
            o1.y = (c1 >> 16)      | ((unsigned int)f2bf(m1h) << 16);
            o2.x = (c2 & 0xFFFFu)  | ((unsigned int)f2bf(m2l) << 16);
            o2.y = (c2 >> 16)      | ((unsigned int)f2bf(m2h) << 16);
            // granule j for o0 = lam>>1; o1 = 16+lam>>1; o2 = 32+lam>>1; half = lam&1
            unsigned int g  = (unsigned int)(lam >> 1);
            unsigned int nw = (unsigned int)nl;
            unsigned int s0 = nw * 48u + (g        + 3u * nw) % 48u;
            unsigned int s1 = nw * 48u + (g + 16u  + 3u * nw) % 48u;
            unsigned int s2 = nw * 48u + (g + 32u  + 3u * nw) % 48u;
            unsigned int half = (unsigned int)(lam & 1);
            l2[2u * s0 + half] = o0;
            l2[2u * s1 + half] = o1;
            l2[2u * s2 + half] = o2;
        }
    }

    __syncthreads();

    // ---- phase 2: GEMM, 4 waves x (96 out x 64 n) = 6x4 frags of 16x16x32 ----
    const unsigned short* aptr = wbf + (size_t)(wv * 96 + r) * K2C + q * 8;

    unsigned int nbase[4], u0[4];
#pragma unroll
    for (int ni = 0; ni < 4; ++ni) {
        unsigned int n = ni * 16 + r;
        nbase[ni] = n * 48u;
        u0[ni] = ((unsigned int)q + 3u * n) % 48u;
    }

    f32x4 acc[6][4];
#pragma unroll
    for (int mi = 0; mi < 6; ++mi)
#pragma unroll
        for (int ni = 0; ni < 4; ++ni)
            acc[mi][ni] = (f32x4){0.f, 0.f, 0.f, 0.f};

#pragma unroll 2
    for (int t = 0; t < 12; ++t) {
        bf16x8 a[6], bb[4];
#pragma unroll
        for (int mi = 0; mi < 6; ++mi)
            a[mi] = *(const bf16x8*)(aptr + (size_t)mi * 16 * K2C + t * 32);
#pragma unroll
        for (int ni = 0; ni < 4; ++ni) {
            unsigned int u = u0[ni] + 4u * t;
            if (u >= 48u) u -= 48u;
            bb[ni] = *(const bf16x8*)(lds + (size_t)(nbase[ni] + u) * 8);
        }
#pragma unroll
        for (int mi = 0; mi < 6; ++mi)
#pragma unroll
            for (int ni = 0; ni < 4; ++ni)
                acc[mi][ni] = __builtin_amdgcn_mfma_f32_16x16x32_bf16(a[mi], bb[ni], acc[mi][ni], 0, 0, 0);
    }

    float* ob = out + (size_t)b * NOUT * NN;
#pragma unroll
    for (int mi = 0; mi < 6; ++mi) {
        int obase = wv * 96 + mi * 16 + q * 4;
#pragma unroll
        for (int ni = 0; ni < 4; ++ni) {
            int n = nt * 64 + ni * 16 + r;
            if (n < NN) {
#pragma unroll
                for (int rr = 0; rr < 4; ++rr) {
                    int o = obase + rr;
                    float val = acc[mi][ni][rr] + bias[o];
                    ob[(size_t)o * NN + n] = fmaxf(val, 0.f);
                }
            }
        }
    }
}

extern "C" void kernel_launch(void* const* d_in, const int* in_sizes, int n_in,
                              void* d_out, int out_size, void* d_ws, size_t ws_size,
                              hipStream_t stream) {
    const float* x    = (const float*)d_in[0];   // [4,192,10000,1]
    const int*   eidx = (const int*)d_in[1];     // [2,4,10000,16]
    const float* w    = (const float*)d_in[2];   // [384,384]
    const float* bias = (const float*)d_in[3];   // [384]
    float* out = (float*)d_out;                  // [4,384,10000,1,1]

    // workspace: xT [4][10000][192] bf16 (15.36 MB) | wbf [384][384] bf16 (0.29 MB)
    unsigned short* xT  = (unsigned short*)d_ws;
    unsigned short* wbf = xT + (size_t)NB * NN * NC;

    hipLaunchKernelGGL(k_prep,  dim3(628 + 144), dim3(256), 0, stream, x, xT, w, wbf);
    hipLaunchKernelGGL(k_fused, dim3(4 * 157),   dim3(256), 0, stream, xT, eidx, wbf, bias, out);
}